// Round 9
// baseline (47.230 us; speedup 1.0000x reference)
//
#include <hip/hip_runtime.h>

#define Bn 512
#define BC 16   // b rows per block
#define JT 32   // j columns per block
// block: 512 threads = 16 bl x 32 jl, one (b,j) pair per thread
// grid (32, 16) = 512 blocks, LDS 34 KB -> 4 blocks/CU = 32 waves/CU

__global__ __launch_bounds__(512, 8) void srap_main(
        const float* __restrict__ scores,
        const float* __restrict__ target,
        float* __restrict__ wsC,
        float* __restrict__ wsT) {
    // scores chunk transposed+packed+swizzled:
    // granule g(k4,b) = k4*16 + (b ^ (k4&15)) holds scores[b0+b][4k4..4k4+3]*C
    __shared__ __align__(16) float sT[(Bn / 4) * BC * 4];   // 32 KB
    __shared__ float partC[8 * BC], partT[8 * BC];

    const int tid = threadIdx.x;          // 0..511
    const int b0 = blockIdx.x * BC;
    const int j0 = blockIdx.y * JT;
    const int jl = tid >> 4;              // local j (0..31)
    const int bl = tid & (BC - 1);        // local b (0..15)

    const float C = 144.26950408889634f;  // log2(e)/tau, tau = 0.01

    // ---- stage scores[b0..b0+15][0..511]*C -> sT (transposed, swizzled) ----
    {
        const int sr = tid >> 5;          // staged b-row 0..15
        const int sk = tid & 31;          // low k4 bits
        const float4* g4 = (const float4*)(scores + (size_t)(b0 + sr) * Bn);
        #pragma unroll
        for (int i = 0; i < 4; ++i) {
            const int k4 = sk + i * 32;
            float4 v = g4[k4];
            v.x *= C; v.y *= C; v.z *= C; v.w *= C;
            const int g = k4 * BC + (sr ^ (k4 & (BC - 1)));
            *(float4*)(&sT[g * 4]) = v;
        }
    }
    __syncthreads();

    const int j = j0 + jl;
    const float tj = scores[(size_t)(b0 + bl) * Bn + j] * C;
    const float4* __restrict__ trow = (const float4*)(target + (size_t)j * Bn);

    float A = 0.0f;  // sum_k sigmoid
    float P = 0.0f;  // sum_k sigmoid * target[j,k]

    #pragma unroll 4
    for (int k4 = 0; k4 < Bn / 4; ++k4) {
        const float4 w = trow[k4];            // few distinct addrs/wave (L1/L2)
        const int g = k4 * BC + (bl ^ (k4 & (BC - 1)));
        const float4 tk = *(const float4*)(&sT[g * 4]);

        // x clamped to +-28: sigma error < 4e-9, product d0..d3 <= 2^113
        float x0 = fmaxf(fminf(tj - tk.x, 28.0f), -28.0f);  // v_med3_f32
        float x1 = fmaxf(fminf(tj - tk.y, 28.0f), -28.0f);
        float x2 = fmaxf(fminf(tj - tk.z, 28.0f), -28.0f);
        float x3 = fmaxf(fminf(tj - tk.w, 28.0f), -28.0f);

        const float d0 = 1.0f + __builtin_amdgcn_exp2f(x0);
        const float d1 = 1.0f + __builtin_amdgcn_exp2f(x1);
        const float d2 = 1.0f + __builtin_amdgcn_exp2f(x2);
        const float d3 = 1.0f + __builtin_amdgcn_exp2f(x3);

        // shared reciprocal: sigma_i = r * cofactor_i, r = 1/(d0 d1 d2 d3)
        const float p01 = d0 * d1;
        const float p23 = d2 * d3;
        const float r = __builtin_amdgcn_rcpf(p01 * p23);
        const float c0 = d1 * p23;
        const float c1 = d0 * p23;
        const float c2 = p01 * d3;
        const float c3 = p01 * d2;

        A = fmaf(r, (c0 + c1) + (c2 + c3), A);
        float u = c0 * w.x;
        u = fmaf(c1, w.y, u);
        u = fmaf(c2, w.z, u);
        u = fmaf(c3, w.w, u);
        P = fmaf(r, u, P);
    }

    // diag k=j contributes exactly 0.5 to A and P (tgt[j,j]=1):
    // sim_all = A + 0.5;  pos = P - 0.5 + target[b,j]
    const float tbj = target[(size_t)(b0 + bl) * Bn + j];
    float c  = (P - 0.5f + tbj) * tbj / (A + 0.5f);
    float tt = tbj;

    // reduce the 4 jl per wave (wave = 4 jl x 16 bl): lanes 0..15 keep sums
    c  += __shfl_down(c, 32);  c  += __shfl_down(c, 16);
    tt += __shfl_down(tt, 32); tt += __shfl_down(tt, 16);
    const int wv = tid >> 6;
    if ((tid & 63) < BC) { partC[wv * BC + bl] = c; partT[wv * BC + bl] = tt; }
    __syncthreads();

    if (tid < BC) {
        float cs = 0.0f, ts = 0.0f;
        #pragma unroll
        for (int w2 = 0; w2 < 8; ++w2) { cs += partC[w2 * BC + tid]; ts += partT[w2 * BC + tid]; }
        wsC[(size_t)blockIdx.y * Bn + b0 + tid] = cs;
        wsT[(size_t)blockIdx.y * Bn + b0 + tid] = ts;
    }
}

__global__ __launch_bounds__(512) void srap_final(
        const float* __restrict__ wsC, const float* __restrict__ wsT,
        float* __restrict__ out) {
    __shared__ float red[8];
    const int b = threadIdx.x;  // 512 threads, one per batch row
    float num = 0.0f, den = 0.0f;
    #pragma unroll
    for (int jt = 0; jt < Bn / JT; ++jt) {
        num += wsC[jt * Bn + b];
        den += wsT[jt * Bn + b];
    }
    float apb = num / den;
    for (int off = 32; off; off >>= 1) apb += __shfl_down(apb, off);
    if ((b & 63) == 0) red[b >> 6] = apb;
    __syncthreads();
    if (b == 0) {
        float s = 0.0f;
        #pragma unroll
        for (int w = 0; w < 8; ++w) s += red[w];
        out[0] = 1.0f - s * (1.0f / Bn);
    }
}

extern "C" void kernel_launch(void* const* d_in, const int* in_sizes, int n_in,
                              void* d_out, int out_size, void* d_ws, size_t ws_size,
                              hipStream_t stream) {
    const float* scores = (const float*)d_in[0];
    const float* target = (const float*)d_in[1];
    float* out = (float*)d_out;
    float* wsC = (float*)d_ws;                       // 16*512 floats
    float* wsT = wsC + (Bn / JT) * Bn;               // 16*512 floats

    srap_main<<<dim3(Bn / BC, Bn / JT), dim3(512), 0, stream>>>(scores, target, wsC, wsT);
    srap_final<<<dim3(1), dim3(512), 0, stream>>>(wsC, wsT, out);
}

// Round 10
// 43.175 us; speedup vs baseline: 1.0939x; 1.0939x over previous
//
#include <hip/hip_runtime.h>

#define Bn 512
#define BC 16   // b rows per block
#define JT 32   // j columns per block
// block: 512 threads = 16 bl x 32 jl, one (b,j) pair per thread
// grid (32, 16) = 512 blocks, LDS 34 KB -> 4 blocks/CU = 32 waves/CU

// sigma(x) = 1/(1+2^x), fast path: Schraudolph exp2 (mean-zero C=486043).
// clamp x to [-126, 30]: x>=30 -> sigma ~ 1e-9 (true ~0); x<=-126 -> e ~ 0 ->
// sigma = 1 exactly as true value. Error only in the ~12% non-saturated pairs,
// |err_sigma| <~ 1.5% zero-mean -> loss error ~2e-3 << 9.9e-3 threshold.
__device__ __forceinline__ float sigfast(float x) {
    float xm = fmaxf(fminf(x, 30.0f), -126.0f);          // v_med3_f32
    float t  = fmaf(xm, 8388608.0f, 1064867173.0f);      // 2^23*x + (127<<23)-C
    float e  = __int_as_float((int)t);                   // v_cvt_i32_f32 + free bitcast
    return __builtin_amdgcn_rcpf(1.0f + e);
}

__global__ __launch_bounds__(512, 8) void srap_main(
        const float* __restrict__ scores,
        const float* __restrict__ target,
        float* __restrict__ wsC,
        float* __restrict__ wsT) {
    // scores chunk transposed+packed+swizzled:
    // granule g(k4,b) = k4*16 + (b ^ (k4&15)) holds scores[b0+b][4k4..4k4+3]*C
    __shared__ __align__(16) float sT[(Bn / 4) * BC * 4];   // 32 KB
    __shared__ float partC[8 * BC], partT[8 * BC];

    const int tid = threadIdx.x;          // 0..511
    const int b0 = blockIdx.x * BC;
    const int j0 = blockIdx.y * JT;
    const int jl = tid >> 4;              // local j (0..31)
    const int bl = tid & (BC - 1);        // local b (0..15)

    const float C = 144.26950408889634f;  // log2(e)/tau, tau = 0.01

    // ---- stage scores[b0..b0+15][0..511]*C -> sT (transposed, swizzled) ----
    {
        const int sr = tid >> 5;          // staged b-row 0..15
        const int sk = tid & 31;          // low k4 bits
        const float4* g4 = (const float4*)(scores + (size_t)(b0 + sr) * Bn);
        #pragma unroll
        for (int i = 0; i < 4; ++i) {
            const int k4 = sk + i * 32;
            float4 v = g4[k4];
            v.x *= C; v.y *= C; v.z *= C; v.w *= C;
            const int g = k4 * BC + (sr ^ (k4 & (BC - 1)));
            *(float4*)(&sT[g * 4]) = v;
        }
    }
    __syncthreads();

    const int j = j0 + jl;
    const float tj = scores[(size_t)(b0 + bl) * Bn + j] * C;
    const float4* __restrict__ trow = (const float4*)(target + (size_t)j * Bn);

    float A0 = 0.0f, A1 = 0.0f;  // sum_k sigmoid (split chains)
    float P0 = 0.0f, P1 = 0.0f;  // sum_k sigmoid * target[j,k]

    #pragma unroll 4
    for (int k4 = 0; k4 < Bn / 4; ++k4) {
        const float4 w = trow[k4];            // few distinct addrs/wave (L1/L2)
        const int g = k4 * BC + (bl ^ (k4 & (BC - 1)));
        const float4 tk = *(const float4*)(&sT[g * 4]);

        float s0 = sigfast(tj - tk.x);
        float s1 = sigfast(tj - tk.y);
        float s2 = sigfast(tj - tk.z);
        float s3 = sigfast(tj - tk.w);
        A0 += s0 + s1;
        A1 += s2 + s3;
        P0 = fmaf(s0, w.x, P0);
        P1 = fmaf(s1, w.y, P1);
        P0 = fmaf(s2, w.z, P0);
        P1 = fmaf(s3, w.w, P1);
    }
    const float A = A0 + A1;
    const float P = P0 + P1;

    // diag k=j contributes ~0.5 to A and P (tgt[j,j]=1):
    // sim_all = A + 0.5;  pos = P - 0.5 + target[b,j]
    const float tbj = target[(size_t)(b0 + bl) * Bn + j];
    float c  = (P - 0.5f + tbj) * tbj / (A + 0.5f);
    float tt = tbj;

    // reduce the 4 jl per wave (wave = 4 jl x 16 bl): lanes 0..15 keep sums
    c  += __shfl_down(c, 32);  c  += __shfl_down(c, 16);
    tt += __shfl_down(tt, 32); tt += __shfl_down(tt, 16);
    const int wv = tid >> 6;
    if ((tid & 63) < BC) { partC[wv * BC + bl] = c; partT[wv * BC + bl] = tt; }
    __syncthreads();

    if (tid < BC) {
        float cs = 0.0f, ts = 0.0f;
        #pragma unroll
        for (int w2 = 0; w2 < 8; ++w2) { cs += partC[w2 * BC + tid]; ts += partT[w2 * BC + tid]; }
        wsC[(size_t)blockIdx.y * Bn + b0 + tid] = cs;
        wsT[(size_t)blockIdx.y * Bn + b0 + tid] = ts;
    }
}

__global__ __launch_bounds__(512) void srap_final(
        const float* __restrict__ wsC, const float* __restrict__ wsT,
        float* __restrict__ out) {
    __shared__ float red[8];
    const int b = threadIdx.x;  // 512 threads, one per batch row
    float num = 0.0f, den = 0.0f;
    #pragma unroll
    for (int jt = 0; jt < Bn / JT; ++jt) {
        num += wsC[jt * Bn + b];
        den += wsT[jt * Bn + b];
    }
    float apb = num / den;
    for (int off = 32; off; off >>= 1) apb += __shfl_down(apb, off);
    if ((b & 63) == 0) red[b >> 6] = apb;
    __syncthreads();
    if (b == 0) {
        float s = 0.0f;
        #pragma unroll
        for (int w = 0; w < 8; ++w) s += red[w];
        out[0] = 1.0f - s * (1.0f / Bn);
    }
}

extern "C" void kernel_launch(void* const* d_in, const int* in_sizes, int n_in,
                              void* d_out, int out_size, void* d_ws, size_t ws_size,
                              hipStream_t stream) {
    const float* scores = (const float*)d_in[0];
    const float* target = (const float*)d_in[1];
    float* out = (float*)d_out;
    float* wsC = (float*)d_ws;                       // 16*512 floats
    float* wsT = wsC + (Bn / JT) * Bn;               // 16*512 floats

    srap_main<<<dim3(Bn / BC, Bn / JT), dim3(512), 0, stream>>>(scores, target, wsC, wsT);
    srap_final<<<dim3(1), dim3(512), 0, stream>>>(wsC, wsT, out);
}

// Round 11
// 39.329 us; speedup vs baseline: 1.2009x; 1.0978x over previous
//
#include <hip/hip_runtime.h>

#define Bn 512
#define BC 16   // b rows per block
#define JT 32   // j columns per block
// block: 1024 threads = 16 bl x 32 jl x 2 k-halves
// grid (32,16) = 512 blocks = 2 blocks/CU -> 32 waves/CU = 8 waves/SIMD

// sigmoid((sk - sj)/tau) = 1 / (1 + exp2(tj - tk)), t = s * log2(e)/tau
__device__ __forceinline__ float sigterm(float tj, float tk) {
    float e = __builtin_amdgcn_exp2f(tj - tk);
    return __builtin_amdgcn_rcpf(1.0f + e);
}

__global__ __launch_bounds__(1024, 8) void srap_main(
        const float* __restrict__ scores,
        const float* __restrict__ target,
        float* __restrict__ wsC,
        float* __restrict__ wsT) {
    // scores chunk transposed+packed+swizzled:
    // granule g(k4,b) = k4*16 + (b ^ (k4&15)) holds scores[b0+b][4k4..4k4+3]*C
    __shared__ __align__(16) float sT[(Bn / 4) * BC * 4];   // 32 KB
    __shared__ float pA[512], pP[512];                       // k-half merge
    __shared__ float partC[8 * BC], partT[8 * BC];

    const int tid = threadIdx.x;          // 0..1023
    const int b0 = blockIdx.x * BC;
    const int j0 = blockIdx.y * JT;
    const int jl = (tid >> 4) & (JT - 1); // local j (0..31)
    const int bl = tid & (BC - 1);        // local b (0..15)
    const int h  = tid >> 9;              // k-half (0,1)

    const float C = 144.26950408889634f;  // log2(e)/tau, tau = 0.01

    // ---- stage scores[b0..b0+15][0..511]*C -> sT (transposed, swizzled) ----
    {
        const int sr = tid >> 6;          // staged b-row 0..15
        const int sk = tid & 63;          // low k4 bits (coalesced 1KB/wave)
        const float4* g4 = (const float4*)(scores + (size_t)(b0 + sr) * Bn);
        #pragma unroll
        for (int i = 0; i < 2; ++i) {
            const int k4 = sk + i * 64;
            float4 v = g4[k4];
            v.x *= C; v.y *= C; v.z *= C; v.w *= C;
            const int g = k4 * BC + (sr ^ (k4 & (BC - 1)));
            *(float4*)(&sT[g * 4]) = v;
        }
    }
    __syncthreads();

    const int j = j0 + jl;
    const float tj = scores[(size_t)(b0 + bl) * Bn + j] * C;
    const float4* __restrict__ trow = (const float4*)(target + (size_t)j * Bn);

    float A0 = 0.0f, A1 = 0.0f;  // sum_k sigmoid (split chains)
    float P0 = 0.0f, P1 = 0.0f;  // sum_k sigmoid * target[j,k]

    const int kb = h * (Bn / 8);          // 64 float4-iters per half
    #pragma unroll 4
    for (int k4 = kb; k4 < kb + Bn / 8; ++k4) {
        const float4 w = trow[k4];            // 4 distinct addrs/wave (L1/L2)
        const int g = k4 * BC + (bl ^ (k4 & (BC - 1)));
        const float4 tk = *(const float4*)(&sT[g * 4]);

        float s0 = sigterm(tj, tk.x);
        float s1 = sigterm(tj, tk.y);
        float s2 = sigterm(tj, tk.z);
        float s3 = sigterm(tj, tk.w);
        A0 += s0 + s1;
        A1 += s2 + s3;
        P0 = fmaf(s0, w.x, P0);
        P1 = fmaf(s1, w.y, P1);
        P0 = fmaf(s2, w.z, P0);
        P1 = fmaf(s3, w.w, P1);
    }
    const float A = A0 + A1;
    const float P = P0 + P1;

    // merge k-halves through LDS (A,P linear in k)
    if (h == 1) { pA[tid & 511] = A; pP[tid & 511] = P; }
    __syncthreads();

    float c = 0.0f, tt = 0.0f;
    if (h == 0) {
        // diag k=j contributes exactly 0.5 to A and P (tgt[j,j]=1, rcp(2)=0.5):
        // sim_all = A_full + 0.5;  pos = P_full - 0.5 + target[b,j]
        const float Af  = A + pA[tid] + 0.5f;
        const float tbj = target[(size_t)(b0 + bl) * Bn + j];
        const float Pf  = P + pP[tid] - 0.5f + tbj;
        c  = (Pf * tbj) / Af;
        tt = tbj;
    }

    // reduce 4 jl per wave (wave = 4 jl x 16 bl); waves 0..7 hold h=0
    c  += __shfl_down(c, 32);  c  += __shfl_down(c, 16);
    tt += __shfl_down(tt, 32); tt += __shfl_down(tt, 16);
    const int wv = tid >> 6;
    if (h == 0 && (tid & 63) < BC) { partC[wv * BC + bl] = c; partT[wv * BC + bl] = tt; }
    __syncthreads();

    if (tid < BC) {
        float cs = 0.0f, ts = 0.0f;
        #pragma unroll
        for (int w2 = 0; w2 < 8; ++w2) { cs += partC[w2 * BC + tid]; ts += partT[w2 * BC + tid]; }
        wsC[(size_t)blockIdx.y * Bn + b0 + tid] = cs;
        wsT[(size_t)blockIdx.y * Bn + b0 + tid] = ts;
    }
}

__global__ __launch_bounds__(512) void srap_final(
        const float* __restrict__ wsC, const float* __restrict__ wsT,
        float* __restrict__ out) {
    __shared__ float red[8];
    const int b = threadIdx.x;  // 512 threads, one per batch row
    float num = 0.0f, den = 0.0f;
    #pragma unroll
    for (int jt = 0; jt < Bn / JT; ++jt) {
        num += wsC[jt * Bn + b];
        den += wsT[jt * Bn + b];
    }
    float apb = num / den;
    for (int off = 32; off; off >>= 1) apb += __shfl_down(apb, off);
    if ((b & 63) == 0) red[b >> 6] = apb;
    __syncthreads();
    if (b == 0) {
        float s = 0.0f;
        #pragma unroll
        for (int w = 0; w < 8; ++w) s += red[w];
        out[0] = 1.0f - s * (1.0f / Bn);
    }
}

extern "C" void kernel_launch(void* const* d_in, const int* in_sizes, int n_in,
                              void* d_out, int out_size, void* d_ws, size_t ws_size,
                              hipStream_t stream) {
    const float* scores = (const float*)d_in[0];
    const float* target = (const float*)d_in[1];
    float* out = (float*)d_out;
    float* wsC = (float*)d_ws;                       // 16*512 floats
    float* wsT = wsC + (Bn / JT) * Bn;               // 16*512 floats

    srap_main<<<dim3(Bn / BC, Bn / JT), dim3(1024), 0, stream>>>(scores, target, wsC, wsT);
    srap_final<<<dim3(1), dim3(512), 0, stream>>>(wsC, wsT, out);
}

// Round 12
// 34.685 us; speedup vs baseline: 1.3617x; 1.1339x over previous
//
#include <hip/hip_runtime.h>

#define Bn 512
#define BC 16   // b rows per block
#define JT 32   // j columns per block
// block: 512 threads = 16 bl x 32 jl, one (b,j) pair per thread
// grid (32,16) = 512 blocks; throughput-bound (R8==R11), so occupancy is moot

typedef float v2f __attribute__((ext_vector_type(2)));

__device__ __forceinline__ v2f pk_add(v2f a, v2f b) {
    v2f d; asm("v_pk_add_f32 %0, %1, %2" : "=v"(d) : "v"(a), "v"(b)); return d;
}
__device__ __forceinline__ void pk_acc(v2f& acc, v2f s) {
    asm("v_pk_add_f32 %0, %1, %0" : "+v"(acc) : "v"(s));
}
__device__ __forceinline__ void pk_fma(v2f& acc, v2f a, v2f b) {
    asm("v_pk_fma_f32 %0, %1, %2, %0" : "+v"(acc) : "v"(a), "v"(b));
}

__global__ __launch_bounds__(512, 8) void srap_main(
        const float* __restrict__ scores,
        const float* __restrict__ target,
        float* __restrict__ wsC,
        float* __restrict__ wsT) {
    // scores chunk transposed+packed+swizzled, NEGATED:
    // granule g(k4,b) = k4*16 + (b ^ (k4&15)) holds -C*scores[b0+b][4k4..4k4+3]
    __shared__ __align__(16) float sT[(Bn / 4) * BC * 4];   // 32 KB
    __shared__ float partC[8 * BC], partT[8 * BC];

    const int tid = threadIdx.x;          // 0..511
    const int b0 = blockIdx.x * BC;
    const int j0 = blockIdx.y * JT;
    const int jl = tid >> 4;              // local j (0..31)
    const int bl = tid & (BC - 1);        // local b (0..15)

    const float C = 144.26950408889634f;  // log2(e)/tau, tau = 0.01

    // ---- stage -C*scores[b0..b0+15][0..511] -> sT (transposed, swizzled) ----
    {
        const int sr = tid >> 5;          // staged b-row 0..15
        const int sk = tid & 31;          // low k4 bits
        const float4* g4 = (const float4*)(scores + (size_t)(b0 + sr) * Bn);
        #pragma unroll
        for (int i = 0; i < 4; ++i) {
            const int k4 = sk + i * 32;
            float4 v = g4[k4];
            v.x *= -C; v.y *= -C; v.z *= -C; v.w *= -C;
            const int g = k4 * BC + (sr ^ (k4 & (BC - 1)));
            *(float4*)(&sT[g * 4]) = v;
        }
    }
    __syncthreads();

    const int j = j0 + jl;
    const float tj = scores[(size_t)(b0 + bl) * Bn + j] * C;
    const v2f tj2 = {tj, tj};
    const v2f one2 = {1.0f, 1.0f};
    const float4* __restrict__ trow = (const float4*)(target + (size_t)j * Bn);

    v2f A01 = {0.0f, 0.0f}, A23 = {0.0f, 0.0f};  // sum_k sigmoid
    v2f P01 = {0.0f, 0.0f}, P23 = {0.0f, 0.0f};  // sum_k sigmoid * tgt[j,k]

    #pragma unroll 4
    for (int k4 = 0; k4 < Bn / 4; ++k4) {
        const float4 w = trow[k4];            // few distinct addrs/wave (L1/L2)
        const int g = k4 * BC + (bl ^ (k4 & (BC - 1)));
        const float4 tk = *(const float4*)(&sT[g * 4]);   // = -tk values

        v2f nk01, nk23, w01, w23;
        __builtin_memcpy(&nk01, &tk.x, 8); __builtin_memcpy(&nk23, &tk.z, 8);
        __builtin_memcpy(&w01, &w.x, 8);   __builtin_memcpy(&w23, &w.z, 8);

        const v2f x01 = pk_add(tj2, nk01);    // x = tj - tk
        const v2f x23 = pk_add(tj2, nk23);
        const float e0 = __builtin_amdgcn_exp2f(x01[0]);
        const float e1 = __builtin_amdgcn_exp2f(x01[1]);
        const float e2 = __builtin_amdgcn_exp2f(x23[0]);
        const float e3 = __builtin_amdgcn_exp2f(x23[1]);
        const v2f e01 = {e0, e1}, e23 = {e2, e3};
        const v2f d01 = pk_add(e01, one2);    // 1 + 2^x
        const v2f d23 = pk_add(e23, one2);
        const float s0 = __builtin_amdgcn_rcpf(d01[0]);
        const float s1 = __builtin_amdgcn_rcpf(d01[1]);
        const float s2 = __builtin_amdgcn_rcpf(d23[0]);
        const float s3 = __builtin_amdgcn_rcpf(d23[1]);
        const v2f s01 = {s0, s1}, s23 = {s2, s3};

        pk_acc(A01, s01);
        pk_acc(A23, s23);
        pk_fma(P01, s01, w01);
        pk_fma(P23, s23, w23);
    }
    const float A = (A01[0] + A01[1]) + (A23[0] + A23[1]);
    const float P = (P01[0] + P01[1]) + (P23[0] + P23[1]);

    // diag k=j contributes exactly 0.5 to A and P (tgt[j,j]=1, rcp(2)=0.5):
    // sim_all = A + 0.5;  pos = P - 0.5 + target[b,j]
    const float tbj = target[(size_t)(b0 + bl) * Bn + j];
    float c  = (P - 0.5f + tbj) * tbj / (A + 0.5f);
    float tt = tbj;

    // reduce the 4 jl per wave (wave = 4 jl x 16 bl): lanes 0..15 keep sums
    c  += __shfl_down(c, 32);  c  += __shfl_down(c, 16);
    tt += __shfl_down(tt, 32); tt += __shfl_down(tt, 16);
    const int wv = tid >> 6;
    if ((tid & 63) < BC) { partC[wv * BC + bl] = c; partT[wv * BC + bl] = tt; }
    __syncthreads();

    if (tid < BC) {
        float cs = 0.0f, ts = 0.0f;
        #pragma unroll
        for (int w2 = 0; w2 < 8; ++w2) { cs += partC[w2 * BC + tid]; ts += partT[w2 * BC + tid]; }
        wsC[(size_t)blockIdx.y * Bn + b0 + tid] = cs;
        wsT[(size_t)blockIdx.y * Bn + b0 + tid] = ts;
    }
}

__global__ __launch_bounds__(512) void srap_final(
        const float* __restrict__ wsC, const float* __restrict__ wsT,
        float* __restrict__ out) {
    __shared__ float red[8];
    const int b = threadIdx.x;  // 512 threads, one per batch row
    float num = 0.0f, den = 0.0f;
    #pragma unroll
    for (int jt = 0; jt < Bn / JT; ++jt) {
        num += wsC[jt * Bn + b];
        den += wsT[jt * Bn + b];
    }
    float apb = num / den;
    for (int off = 32; off; off >>= 1) apb += __shfl_down(apb, off);
    if ((b & 63) == 0) red[b >> 6] = apb;
    __syncthreads();
    if (b == 0) {
        float s = 0.0f;
        #pragma unroll
        for (int w = 0; w < 8; ++w) s += red[w];
        out[0] = 1.0f - s * (1.0f / Bn);
    }
}

extern "C" void kernel_launch(void* const* d_in, const int* in_sizes, int n_in,
                              void* d_out, int out_size, void* d_ws, size_t ws_size,
                              hipStream_t stream) {
    const float* scores = (const float*)d_in[0];
    const float* target = (const float*)d_in[1];
    float* out = (float*)d_out;
    float* wsC = (float*)d_ws;                       // 16*512 floats
    float* wsT = wsC + (Bn / JT) * Bn;               // 16*512 floats

    srap_main<<<dim3(Bn / BC, Bn / JT), dim3(512), 0, stream>>>(scores, target, wsC, wsT);
    srap_final<<<dim3(1), dim3(512), 0, stream>>>(wsC, wsT, out);
}